// Round 9
// baseline (461.911 us; speedup 1.0000x reference)
//
#include <hip/hip_runtime.h>
#include <stdint.h>
#include <stddef.h>

// Problem: X=2048, Y=256, F=128, H=8, NF=32, O=H*NF=256. f32 I/O, mask int32.
//
// Round 9 = round 8 + column-split wave tiles (LDS-BW attack):
//  - 1024-thread block (16 waves); wave w -> rg=w>>1 (rows [32rg,32rg+32)),
//    cg=w&1 (cols [128cg,128cg+128)). Per-wave B-read halves vs round 8.
//  - acc[2][8]=64 regs, ah[2][4]=32, araw transient; peak ~110 < 128-reg cap
//  - LN stats: per-cg partials + LDS exchange; stats barrier doubles as the
//    softmax-visibility barrier -> still 3 barriers per x
//  - logits balanced: every wave does 4 MFMAs for its 16-row slice (rows 32rg+16cg)
//  - f16 single-pass MFMA; algebraic epilogue (gamma/beta at final store)

typedef __attribute__((ext_vector_type(8))) _Float16 f16x8;  // 4 VGPRs
typedef __attribute__((ext_vector_type(8))) float f32x8;
typedef __attribute__((ext_vector_type(4))) float f32x4;

#define XPB 8
#define NBLK 256

// dynamic LDS layout (bytes)
#define OFF_W1   0u        // 65536: W1 f16 fragments [(ntg*4+kk)][l][8], ntg 0..15
#define OFF_W2   65536u    // 4096 : W2 f16 fragments [kk][l][8] (cols 8..15 = 0)
#define OFF_COEF 69632u    // 8224 : float[8][257] logits -> coefs (head-major, padded)
#define OFF_OUTP 77856u    // 8192 : float[16][128] per-wave output partials
#define OFF_SNQ  86048u    // 4096 : float snqS[256][2], snqQ[256][2]
#define OFF_B1   90144u    // 1024 : float[256]
#define OFF_G    91168u    // 1024
#define OFF_BT   92192u    // 1024
#define OFF_B2   93216u    // 64   : float[16]
#define LDS_BYTES 93280u

__device__ __forceinline__ f32x4 mfma16(f16x8 a, f16x8 b, f32x4 c){
  return __builtin_amdgcn_mfma_f32_16x16x32_f16(a, b, c, 0, 0, 0);
}

__global__ __launch_bounds__(1024, 4) void attn_main(
    const float* __restrict__ xy, const int* __restrict__ mask,
    const float* __restrict__ W1g, const float* __restrict__ b1g,
    const float* __restrict__ gammag, const float* __restrict__ betag,
    const float* __restrict__ W2g, const float* __restrict__ b2g,
    float* __restrict__ out)
{
  extern __shared__ char smem[];
  const int tid = threadIdx.x;
  const int l  = tid & 63;
  const int w  = tid >> 6;     // wave 0..15
  const int rg = w >> 1;       // row group 0..7 : rows [32rg, 32rg+32)
  const int cg = w & 1;        // col group 0..1 : cols [128cg, 128cg+128)
  const int lg = l >> 4;       // lane group 0..3
  const int lc = l & 15;

  _Float16* w1f = (_Float16*)(smem + OFF_W1);
  _Float16* w2f = (_Float16*)(smem + OFF_W2);
  float* coefT = (float*)(smem + OFF_COEF);           // [8][257]
  float* outp  = (float*)(smem + OFF_OUTP);           // [16][128]
  float* snqS  = (float*)(smem + OFF_SNQ);            // [256][2]
  float* snqQ  = (float*)(smem + OFF_SNQ + 2048u);    // [256][2]
  float* ldsB1 = (float*)(smem + OFF_B1);
  float* ldsG  = (float*)(smem + OFF_G);
  float* ldsBt = (float*)(smem + OFF_BT);
  float* ldsB2 = (float*)(smem + OFF_B2);

  if (tid < 256){
    ldsB1[tid] = b1g[tid];
    ldsG[tid]  = gammag[tid];
    ldsBt[tid] = betag[tid];
  }
  if (tid < 16) ldsB2[tid] = (tid < 8) ? b2g[tid] : 0.f;

  // ---- gather W1 (f32) -> f16 fragment order (1024 threads, 4 rounds):
  //      idx=((ntg*4+kk)*64+l)*8+j, value=W1[f][o], f=kk*32+(l>>4)*8+j, o=ntg*16+(l&15)
  #pragma unroll
  for (int i = 0; i < 4; ++i){
    int base = i * 8192 + tid * 8;
    int bl  = (base >> 3) & 63;
    int bkk = (base >> 9) & 3;
    int bnt = base >> 11;
    int o   = bnt * 16 + (bl & 15);
    int f0  = bkk * 32 + ((bl >> 4) << 3);
    f16x8 v;
    #pragma unroll
    for (int j = 0; j < 8; ++j) v[j] = (_Float16)W1g[(size_t)(f0 + j) * 256 + o];
    *(f16x8*)(w1f + base) = v;
  }
  // ---- gather W2 -> f16 fragments (pad cols 8..15 with zero) ----
  if (tid < 256){
    int base = tid * 8;
    int bl  = (base >> 3) & 63;
    int bkk = base >> 9;
    int h   = bl & 15;
    int f0  = bkk * 32 + ((bl >> 4) << 3);
    f16x8 v;
    #pragma unroll
    for (int j = 0; j < 8; ++j)
      v[j] = (h < 8) ? (_Float16)W2g[(size_t)(f0 + j) * 8 + h] : (_Float16)0.f;
    *(f16x8*)(w2f + base) = v;
  }
  __syncthreads();   // gathers + params visible

  const int x0 = blockIdx.x * XPB;

  for (int xi = 0; xi < XPB; ++xi){
    const int x = x0 + xi;

    // ---- A rows [32rg,32rg+32) (cg twin L2-hits the same lines) + mask ----
    f32x8 araw[2][4];
    #pragma unroll
    for (int rt = 0; rt < 2; ++rt)
      #pragma unroll
      for (int kk = 0; kk < 4; ++kk)
        araw[rt][kk] = *(const f32x8*)(xy + (((size_t)x * 256 + rg * 32 + rt * 16 + lc) << 7)
                                          + kk * 32 + (lg << 3));
    int mk[4];
    if (w < 8){
      #pragma unroll
      for (int k = 0; k < 4; ++k) mk[k] = mask[(x << 8) + (k << 6) + l];
    }

    // ---- leaky_relu (f32-exact) + convert to f16 (araw dies here) ----
    f16x8 ah[2][4];
    #pragma unroll
    for (int rt = 0; rt < 2; ++rt)
      #pragma unroll
      for (int kk = 0; kk < 4; ++kk){
        f32x8 v = araw[rt][kk];
        f16x8 vh;
        #pragma unroll
        for (int j = 0; j < 8; ++j){
          float f = fmaxf(v[j], 0.f) + 0.01f * fminf(v[j], 0.f);
          vh[j] = (_Float16)f;
        }
        ah[rt][kk] = vh;
      }

    // ---- logits for rows [32rg+16cg, +16): 4 MFMA per wave, all waves busy ----
    {
      f32x4 la = {0.f,0.f,0.f,0.f};
      #pragma unroll
      for (int kk = 0; kk < 4; ++kk){
        f16x8 wb = *(const f16x8*)(w2f + (kk * 64 + l) * 8);
        la = mfma16(ah[cg][kk], wb, la);
      }
      if (lc < 8){
        float b2v = ldsB2[lc];
        #pragma unroll
        for (int r = 0; r < 4; ++r){
          int row = rg * 32 + cg * 16 + (lg << 2) + r;  // C/D: row=(l>>4)*4+r, col=l&15
          coefT[lc * 257 + row] = la[r] + b2v;
        }
      }
    }
    __syncthreads();   // B1: all logits visible

    // ---- softmax over Y for head w (waves 0-7; mask-fill logits with 0);
    //      other waves proceed to GEMM -> softmax latency overlapped ----
    if (w < 8){
      float lgv[4];
      #pragma unroll
      for (int k = 0; k < 4; ++k){
        float v = coefT[w * 257 + (k << 6) + l];
        lgv[k] = mk[k] ? 0.f : v;
      }
      float mx = fmaxf(fmaxf(lgv[0], lgv[1]), fmaxf(lgv[2], lgv[3]));
      #pragma unroll
      for (int mm = 1; mm < 64; mm <<= 1) mx = fmaxf(mx, __shfl_xor(mx, mm));
      float e[4]; float sum = 0.f;
      #pragma unroll
      for (int k = 0; k < 4; ++k){ e[k] = __expf(lgv[k] - mx); sum += e[k]; }
      #pragma unroll
      for (int mm = 1; mm < 64; mm <<= 1) sum += __shfl_xor(sum, mm);
      float inv = 1.f / sum;
      #pragma unroll
      for (int k = 0; k < 4; ++k) coefT[w * 257 + (k << 6) + l] = e[k] * inv;
    }

    // ---- GEMM: acc[rt][nt], rows 32rg+16rt+4lg+r, col 128cg+16nt+lc ----
    f32x4 acc[2][8];
    #pragma unroll
    for (int rt = 0; rt < 2; ++rt)
      #pragma unroll
      for (int nt = 0; nt < 8; ++nt)
        acc[rt][nt] = (f32x4){0.f,0.f,0.f,0.f};

    #pragma unroll
    for (int nt = 0; nt < 8; ++nt){
      int ntg = cg * 8 + nt;
      #pragma unroll
      for (int kk = 0; kk < 4; ++kk){
        f16x8 b = *(const f16x8*)(w1f + ((ntg * 4 + kk) * 64 + l) * 8);
        acc[0][nt] = mfma16(ah[0][kk], b, acc[0][nt]);
        acc[1][nt] = mfma16(ah[1][kk], b, acc[1][nt]);
      }
    }

    // ---- hid = acc + b1; per-cg LN partials (butterfly over lc bits) ----
    float s[2][4] = {{0,0,0,0},{0,0,0,0}}, q[2][4] = {{0,0,0,0},{0,0,0,0}};
    #pragma unroll
    for (int nt = 0; nt < 8; ++nt){
      float bv = ldsB1[cg * 128 + nt * 16 + lc];
      #pragma unroll
      for (int rt = 0; rt < 2; ++rt)
        #pragma unroll
        for (int r = 0; r < 4; ++r){
          float v = acc[rt][nt][r] + bv;
          acc[rt][nt][r] = v;
          s[rt][r] += v;
          q[rt][r] = fmaf(v, v, q[rt][r]);
        }
    }
    #pragma unroll
    for (int mm = 1; mm <= 8; mm <<= 1){
      #pragma unroll
      for (int rt = 0; rt < 2; ++rt)
        #pragma unroll
        for (int r = 0; r < 4; ++r){
          s[rt][r] += __shfl_xor(s[rt][r], mm);
          q[rt][r] += __shfl_xor(q[rt][r], mm);
        }
    }
    if (lc == 0){
      #pragma unroll
      for (int rt = 0; rt < 2; ++rt)
        #pragma unroll
        for (int r = 0; r < 4; ++r){
          int row = rg * 32 + rt * 16 + (lg << 2) + r;
          snqS[row * 2 + cg] = s[rt][r];
          snqQ[row * 2 + cg] = q[rt][r];
        }
    }
    __syncthreads();   // B2: stats partials + softmax coefs visible

    // ---- combine stats -> mu/rstd per row ----
    float mu[2][4], rstd[2][4];
    #pragma unroll
    for (int rt = 0; rt < 2; ++rt)
      #pragma unroll
      for (int r = 0; r < 4; ++r){
        int row = rg * 32 + rt * 16 + (lg << 2) + r;
        float st = snqS[row * 2] + snqS[row * 2 + 1];
        float qt = snqQ[row * 2] + snqQ[row * 2 + 1];
        float m = st * (1.f / 256.f);
        float var = qt * (1.f / 256.f) - m * m;
        mu[rt][r] = m;
        rstd[rt][r] = rsqrtf(fmaxf(var, 0.f) + 1e-5f);
      }

    // ---- contraction: partial[col] = sum_{rows} coef*rstd*(hid - mu) ----
    #pragma unroll
    for (int h0 = 0; h0 < 4; ++h0){
      int h = cg * 4 + h0;               // head of col 128cg+16nt+lc is 4cg+(nt>>1)
      float c2[2][4];
      float Dl = 0.f;
      #pragma unroll
      for (int rt = 0; rt < 2; ++rt)
        #pragma unroll
        for (int r = 0; r < 4; ++r){
          float c = coefT[h * 257 + rg * 32 + rt * 16 + (lg << 2) + r];
          float v = c * rstd[rt][r];
          c2[rt][r] = v;
          Dl = fmaf(v, mu[rt][r], Dl);
        }
      #pragma unroll
      for (int t = 0; t < 2; ++t){
        int nt = h0 * 2 + t;
        float p = -Dl;
        #pragma unroll
        for (int rt = 0; rt < 2; ++rt)
          #pragma unroll
          for (int r = 0; r < 4; ++r)
            p = fmaf(c2[rt][r], acc[rt][nt][r], p);
        p += __shfl_xor(p, 16);
        p += __shfl_xor(p, 32);
        if (lg == 0) outp[w * 128 + nt * 16 + lc] = p;
      }
    }
    __syncthreads();   // B3: outp partials visible

    // ---- cross-rowgroup reduce, apply gamma/beta, f32 store ----
    if (tid < 256){
      int cgc = tid >> 7, ci = tid & 127;
      float S = 0.f;
      #pragma unroll
      for (int r8 = 0; r8 < 8; ++r8) S += outp[(r8 * 2 + cgc) * 128 + ci];
      out[((size_t)x << 8) + tid] = fmaf(ldsG[tid], S, ldsBt[tid]);
    }
  }
}

extern "C" void kernel_launch(void* const* d_in, const int* in_sizes, int n_in,
                              void* d_out, int out_size, void* d_ws, size_t ws_size,
                              hipStream_t stream){
  (void)in_sizes; (void)n_in; (void)out_size; (void)d_ws; (void)ws_size;
  const float* xy    = (const float*)d_in[0];
  const int*   mask  = (const int*)d_in[1];
  const float* W1    = (const float*)d_in[2];
  const float* b1    = (const float*)d_in[3];
  const float* gamma = (const float*)d_in[4];
  const float* beta  = (const float*)d_in[5];
  const float* W2    = (const float*)d_in[6];
  const float* b2    = (const float*)d_in[7];

  hipFuncSetAttribute((const void*)attn_main,
                      hipFuncAttributeMaxDynamicSharedMemorySize, (int)LDS_BYTES);
  attn_main<<<NBLK, 1024, LDS_BYTES, stream>>>(xy, mask, W1, b1, gamma, beta, W2, b2,
                                               (float*)d_out);
}

// Round 10
// 208.006 us; speedup vs baseline: 2.2207x; 2.2207x over previous
//
#include <hip/hip_runtime.h>
#include <stdint.h>
#include <stddef.h>

// Problem: X=2048, Y=256, F=128, H=8, NF=32, O=H*NF=256. f32 I/O, mask int32.
//
// Round 10 = round-8 register discipline + round-9 tiling via A-in-LDS:
//  - 1024-thread block (16 waves), 4 waves/SIMD. Unified reg budget 128/wave
//    splits 64 AGPR (acc) + 64 arch; every phase keeps arch live-set < 64.
//  - Convert: wave w leaky+f16-converts rows [16w,16w+16) ONCE (araw 32 + ah 16
//    arch regs), writes fragment tile to LDS, computes those rows' logits.
//  - GEMM: wave (rg=w>>1, cg=w&1) owns rows [32rg,+32) x cols [128cg,+128);
//    A re-read from LDS (8 KB/wave), B 32 KB/wave -> block LDS ~0.7 MB/x
//    (round 8: ~1.1 MB/x); convert VALU halved (no cg duplication).
//  - LN stats per-cg partials + snq LDS exchange; 3 barriers per x.
//  - f16 single-pass MFMA; algebraic epilogue (gamma/beta at final store).

typedef __attribute__((ext_vector_type(8))) _Float16 f16x8;  // 4 VGPRs
typedef __attribute__((ext_vector_type(8))) float f32x8;
typedef __attribute__((ext_vector_type(4))) float f32x4;

#define XPB 8
#define NBLK 256

// dynamic LDS layout (bytes) — total 158816 < 163840
#define OFF_W1   0u        // 65536: W1 f16 fragments [(ntg*4+kk)][l][8], ntg 0..15
#define OFF_W2   65536u    // 4096 : W2 f16 fragments [kk][l][8] (cols 8..15 = 0)
#define OFF_A    69632u    // 65536: A  f16 fragments [(tile*4+kk)][l][8], tile 0..15
#define OFF_COEF 135168u   // 8224 : float[8][257] logits -> coefs (head-major, padded)
#define OFF_OUTP 143392u   // 8192 : float[16][128] per-wave output partials
#define OFF_SNQ  151584u   // 4096 : float snqS[256][2], snqQ[256][2]
#define OFF_B1   155680u   // 1024 : float[256]
#define OFF_G    156704u   // 1024
#define OFF_BT   157728u   // 1024
#define OFF_B2   158752u   // 64   : float[16]
#define LDS_BYTES 158816u

__device__ __forceinline__ f32x4 mfma16(f16x8 a, f16x8 b, f32x4 c){
  return __builtin_amdgcn_mfma_f32_16x16x32_f16(a, b, c, 0, 0, 0);
}

__global__ __launch_bounds__(1024, 4) void attn_main(
    const float* __restrict__ xy, const int* __restrict__ mask,
    const float* __restrict__ W1g, const float* __restrict__ b1g,
    const float* __restrict__ gammag, const float* __restrict__ betag,
    const float* __restrict__ W2g, const float* __restrict__ b2g,
    float* __restrict__ out)
{
  extern __shared__ char smem[];
  const int tid = threadIdx.x;
  const int l  = tid & 63;
  const int w  = tid >> 6;     // wave 0..15
  const int rg = w >> 1;       // GEMM row group: rows [32rg, 32rg+32)
  const int cg = w & 1;        // GEMM col group: cols [128cg, 128cg+128)
  const int lg = l >> 4;       // lane group 0..3
  const int lc = l & 15;

  _Float16* w1f = (_Float16*)(smem + OFF_W1);
  _Float16* w2f = (_Float16*)(smem + OFF_W2);
  _Float16* af  = (_Float16*)(smem + OFF_A);
  float* coefT = (float*)(smem + OFF_COEF);           // [8][257]
  float* outp  = (float*)(smem + OFF_OUTP);           // [16][128]
  float* snqS  = (float*)(smem + OFF_SNQ);            // [256][2]
  float* snqQ  = (float*)(smem + OFF_SNQ + 2048u);    // [256][2]
  float* ldsB1 = (float*)(smem + OFF_B1);
  float* ldsG  = (float*)(smem + OFF_G);
  float* ldsBt = (float*)(smem + OFF_BT);
  float* ldsB2 = (float*)(smem + OFF_B2);

  if (tid < 256){
    ldsB1[tid] = b1g[tid];
    ldsG[tid]  = gammag[tid];
    ldsBt[tid] = betag[tid];
  }
  if (tid < 16) ldsB2[tid] = (tid < 8) ? b2g[tid] : 0.f;

  // ---- gather W1 (f32) -> f16 fragment order (1024 threads, 4 rounds):
  //      idx=((ntg*4+kk)*64+l)*8+j, value=W1[f][o], f=kk*32+(l>>4)*8+j, o=ntg*16+(l&15)
  #pragma unroll
  for (int i = 0; i < 4; ++i){
    int base = i * 8192 + tid * 8;
    int bl  = (base >> 3) & 63;
    int bkk = (base >> 9) & 3;
    int bnt = base >> 11;
    int o   = bnt * 16 + (bl & 15);
    int f0  = bkk * 32 + ((bl >> 4) << 3);
    f16x8 v;
    #pragma unroll
    for (int j = 0; j < 8; ++j) v[j] = (_Float16)W1g[(size_t)(f0 + j) * 256 + o];
    *(f16x8*)(w1f + base) = v;
  }
  // ---- gather W2 -> f16 fragments (pad cols 8..15 with zero) ----
  if (tid < 256){
    int base = tid * 8;
    int bl  = (base >> 3) & 63;
    int bkk = base >> 9;
    int h   = bl & 15;
    int f0  = bkk * 32 + ((bl >> 4) << 3);
    f16x8 v;
    #pragma unroll
    for (int j = 0; j < 8; ++j)
      v[j] = (h < 8) ? (_Float16)W2g[(size_t)(f0 + j) * 8 + h] : (_Float16)0.f;
    *(f16x8*)(w2f + base) = v;
  }
  __syncthreads();   // gathers + params visible

  const int x0 = blockIdx.x * XPB;

  for (int xi = 0; xi < XPB; ++xi){
    const int x = x0 + xi;

    // ---- convert: wave w handles rows [16w,16w+16) once (no duplication) ----
    f32x8 araw[4];
    #pragma unroll
    for (int kk = 0; kk < 4; ++kk)
      araw[kk] = *(const f32x8*)(xy + (((size_t)x * 256 + w * 16 + lc) << 7)
                                    + kk * 32 + (lg << 3));
    int mk[4];
    if (w < 8){
      #pragma unroll
      for (int k = 0; k < 4; ++k) mk[k] = mask[(x << 8) + (k << 6) + l];
    }

    f16x8 ah[4];
    #pragma unroll
    for (int kk = 0; kk < 4; ++kk){
      f32x8 v = araw[kk];
      f16x8 vh;
      #pragma unroll
      for (int j = 0; j < 8; ++j){
        float f = fmaxf(v[j], 0.f) + 0.01f * fminf(v[j], 0.f);
        vh[j] = (_Float16)f;
      }
      ah[kk] = vh;
      *(f16x8*)(af + ((w * 4 + kk) * 64 + l) * 8) = vh;   // A tile w -> LDS
    }

    // ---- logits for rows [16w,16w+16): 4 MFMA from regs; all waves busy ----
    {
      f32x4 la = {0.f,0.f,0.f,0.f};
      #pragma unroll
      for (int kk = 0; kk < 4; ++kk){
        f16x8 wb = *(const f16x8*)(w2f + (kk * 64 + l) * 8);
        la = mfma16(ah[kk], wb, la);
      }
      if (lc < 8){
        float b2v = ldsB2[lc];
        #pragma unroll
        for (int r = 0; r < 4; ++r){
          int row = (w << 4) + (lg << 2) + r;   // C/D: row=(l>>4)*4+r, col=l&15 (head)
          coefT[lc * 257 + row] = la[r] + b2v;
        }
      }
    }
    __syncthreads();   // B1: A fragments + all logits visible

    // ---- softmax over Y for head w (waves 0-7; mask-fill logits with 0);
    //      other waves proceed to GEMM -> softmax latency overlapped ----
    if (w < 8){
      float lgv[4];
      #pragma unroll
      for (int k = 0; k < 4; ++k){
        float v = coefT[w * 257 + (k << 6) + l];
        lgv[k] = mk[k] ? 0.f : v;
      }
      float mx = fmaxf(fmaxf(lgv[0], lgv[1]), fmaxf(lgv[2], lgv[3]));
      #pragma unroll
      for (int mm = 1; mm < 64; mm <<= 1) mx = fmaxf(mx, __shfl_xor(mx, mm));
      float e[4]; float sum = 0.f;
      #pragma unroll
      for (int k = 0; k < 4; ++k){ e[k] = __expf(lgv[k] - mx); sum += e[k]; }
      #pragma unroll
      for (int mm = 1; mm < 64; mm <<= 1) sum += __shfl_xor(sum, mm);
      float inv = 1.f / sum;
      #pragma unroll
      for (int k = 0; k < 4; ++k) coefT[w * 257 + (k << 6) + l] = e[k] * inv;
    }

    // ---- GEMM: acc[rt][nt], rows 32rg+16rt+4lg+r, col 128cg+16nt+lc;
    //      A from LDS (tiles 2rg,2rg+1), each B fragment feeds 2 MFMAs ----
    f32x4 acc[2][8];
    #pragma unroll
    for (int rt = 0; rt < 2; ++rt)
      #pragma unroll
      for (int nt = 0; nt < 8; ++nt)
        acc[rt][nt] = (f32x4){0.f,0.f,0.f,0.f};

    #pragma unroll
    for (int kk = 0; kk < 4; ++kk){
      f16x8 a0 = *(const f16x8*)(af + (((2 * rg    ) * 4 + kk) * 64 + l) * 8);
      f16x8 a1 = *(const f16x8*)(af + (((2 * rg + 1) * 4 + kk) * 64 + l) * 8);
      #pragma unroll
      for (int nt = 0; nt < 8; ++nt){
        f16x8 b = *(const f16x8*)(w1f + (((cg * 8 + nt) * 4 + kk) * 64 + l) * 8);
        acc[0][nt] = mfma16(a0, b, acc[0][nt]);
        acc[1][nt] = mfma16(a1, b, acc[1][nt]);
      }
    }

    // ---- hid = acc + b1; per-cg LN partials (butterfly over lc bits) ----
    float s[2][4] = {{0,0,0,0},{0,0,0,0}}, q[2][4] = {{0,0,0,0},{0,0,0,0}};
    #pragma unroll
    for (int nt = 0; nt < 8; ++nt){
      float bv = ldsB1[cg * 128 + nt * 16 + lc];
      #pragma unroll
      for (int rt = 0; rt < 2; ++rt)
        #pragma unroll
        for (int r = 0; r < 4; ++r){
          float v = acc[rt][nt][r] + bv;
          acc[rt][nt][r] = v;
          s[rt][r] += v;
          q[rt][r] = fmaf(v, v, q[rt][r]);
        }
    }
    #pragma unroll
    for (int mm = 1; mm <= 8; mm <<= 1){
      #pragma unroll
      for (int rt = 0; rt < 2; ++rt)
        #pragma unroll
        for (int r = 0; r < 4; ++r){
          s[rt][r] += __shfl_xor(s[rt][r], mm);
          q[rt][r] += __shfl_xor(q[rt][r], mm);
        }
    }
    if (lc == 0){
      #pragma unroll
      for (int rt = 0; rt < 2; ++rt)
        #pragma unroll
        for (int r = 0; r < 4; ++r){
          int row = rg * 32 + rt * 16 + (lg << 2) + r;
          snqS[row * 2 + cg] = s[rt][r];
          snqQ[row * 2 + cg] = q[rt][r];
        }
    }
    __syncthreads();   // B2: stats partials + softmax coefs visible

    // ---- combine stats -> mu/rstd per row ----
    float mu[2][4], rstd[2][4];
    #pragma unroll
    for (int rt = 0; rt < 2; ++rt)
      #pragma unroll
      for (int r = 0; r < 4; ++r){
        int row = rg * 32 + rt * 16 + (lg << 2) + r;
        float st = snqS[row * 2] + snqS[row * 2 + 1];
        float qt = snqQ[row * 2] + snqQ[row * 2 + 1];
        float m = st * (1.f / 256.f);
        float var = qt * (1.f / 256.f) - m * m;
        mu[rt][r] = m;
        rstd[rt][r] = rsqrtf(fmaxf(var, 0.f) + 1e-5f);
      }

    // ---- contraction: partial[col] = sum_{rows} coef*rstd*(hid - mu) ----
    #pragma unroll
    for (int h0 = 0; h0 < 4; ++h0){
      int h = cg * 4 + h0;               // head of col 128cg+16nt+lc is 4cg+(nt>>1)
      float c2[2][4];
      float Dl = 0.f;
      #pragma unroll
      for (int rt = 0; rt < 2; ++rt)
        #pragma unroll
        for (int r = 0; r < 4; ++r){
          float c = coefT[h * 257 + rg * 32 + rt * 16 + (lg << 2) + r];
          float v = c * rstd[rt][r];
          c2[rt][r] = v;
          Dl = fmaf(v, mu[rt][r], Dl);
        }
      #pragma unroll
      for (int t = 0; t < 2; ++t){
        int nt = h0 * 2 + t;
        float p = -Dl;
        #pragma unroll
        for (int rt = 0; rt < 2; ++rt)
          #pragma unroll
          for (int r = 0; r < 4; ++r)
            p = fmaf(c2[rt][r], acc[rt][nt][r], p);
        p += __shfl_xor(p, 16);
        p += __shfl_xor(p, 32);
        if (lg == 0) outp[w * 128 + nt * 16 + lc] = p;
      }
    }
    __syncthreads();   // B3: outp partials visible

    // ---- cross-rowgroup reduce, apply gamma/beta, f32 store ----
    if (tid < 256){
      int cgc = tid >> 7, ci = tid & 127;
      float S = 0.f;
      #pragma unroll
      for (int r8 = 0; r8 < 8; ++r8) S += outp[(r8 * 2 + cgc) * 128 + ci];
      out[((size_t)x << 8) + tid] = fmaf(ldsG[tid], S, ldsBt[tid]);
    }
  }
}

extern "C" void kernel_launch(void* const* d_in, const int* in_sizes, int n_in,
                              void* d_out, int out_size, void* d_ws, size_t ws_size,
                              hipStream_t stream){
  (void)in_sizes; (void)n_in; (void)out_size; (void)d_ws; (void)ws_size;
  const float* xy    = (const float*)d_in[0];
  const int*   mask  = (const int*)d_in[1];
  const float* W1    = (const float*)d_in[2];
  const float* b1    = (const float*)d_in[3];
  const float* gamma = (const float*)d_in[4];
  const float* beta  = (const float*)d_in[5];
  const float* W2    = (const float*)d_in[6];
  const float* b2    = (const float*)d_in[7];

  hipFuncSetAttribute((const void*)attn_main,
                      hipFuncAttributeMaxDynamicSharedMemorySize, (int)LDS_BYTES);
  attn_main<<<NBLK, 1024, LDS_BYTES, stream>>>(xy, mask, W1, b1, gamma, beta, W2, b2,
                                               (float*)d_out);
}